// Round 13
// baseline (131.195 us; speedup 1.0000x reference)
//
#include <hip/hip_runtime.h>

// Problem shape (fixed by reference): N=64, C=1024, H=W=28 -> HW=784
#define HWD 784
#define Q4  196            // HWD/4 float4 slots per channel row
#define CD  1024
#define ND  64

typedef float f32x4 __attribute__((ext_vector_type(4)));

__device__ __forceinline__ float4 cam4(float4 v, float wc) {
    float4 r;
    r.x = fmaxf(v.x * wc, 0.f);
    r.y = fmaxf(v.y * wc, 0.f);
    r.z = fmaxf(v.z * wc, 0.f);
    r.w = fmaxf(v.w * wc, 0.f);
    return r;
}
__device__ __forceinline__ float max4(float4 v) {
    return fmaxf(fmaxf(v.x, v.y), fmaxf(v.z, v.w));
}
__device__ __forceinline__ void accdrop(float4& a, float4 c, float thr) {
    a.x += (c.x > thr) ? 0.f : c.x;
    a.y += (c.y > thr) ? 0.f : c.y;
    a.z += (c.z > thr) ? 0.f : c.z;
    a.w += (c.w > thr) ? 0.f : c.w;
}

// ---------------------------------------------------------------------------
// Pass 1 v5: NO LDS, NO barriers. Block = 128 threads = 2 INDEPENDENT waves.
// Each wave: cpw consecutive channels, one per iteration (4 float4 loads in
// flight, thr_kernel's proven streaming shape), dropped-sum accumulated in
// 4 float4 registers, then stored DIRECTLY from registers as 4 float4
// stores into its own Spart row. Wave churn matches thr_kernel (~33us for
// this same 205MB read).
// ---------------------------------------------------------------------------
__global__ void __launch_bounds__(128) pass1_kernel(const float* __restrict__ x,
                                                    const float* __restrict__ w,
                                                    const float* __restrict__ mu_p,
                                                    float* __restrict__ Spart,
                                                    int cpw) {
    const int t = threadIdx.x;
    const int wave = t >> 6;
    const int lane = t & 63;
    const int n = blockIdx.y;
    const int chunk = blockIdx.x * 2 + wave;
    const int cbase = chunk * cpw;
    const float mu = mu_p[0];

    const float4* rows = reinterpret_cast<const float4*>(x + ((size_t)n * CD + cbase) * HWD);

    float4 acc0 = {0.f,0.f,0.f,0.f}, acc1 = {0.f,0.f,0.f,0.f};
    float4 acc2 = {0.f,0.f,0.f,0.f}, acc3 = {0.f,0.f,0.f,0.f};

    #pragma unroll 1
    for (int j = 0; j < cpw; ++j) {
        const float4* r = rows + j * Q4;
        float4 v0 = r[lane];
        float4 v1 = r[lane + 64];
        float4 v2 = r[lane + 128];
        float4 v3 = (lane < 4) ? r[192 + lane] : float4{0.f,0.f,0.f,0.f};
        const float wc = w[cbase + j];

        v0 = cam4(v0, wc); v1 = cam4(v1, wc); v2 = cam4(v2, wc); v3 = cam4(v3, wc);

        float m = fmaxf(fmaxf(max4(v0), max4(v1)), fmaxf(max4(v2), max4(v3)));
        #pragma unroll
        for (int off = 32; off > 0; off >>= 1)
            m = fmaxf(m, __shfl_xor(m, off, 64));
        const float thr = m * mu;

        accdrop(acc0, v0, thr);
        accdrop(acc1, v1, thr);
        accdrop(acc2, v2, thr);
        accdrop(acc3, v3, thr);      // zeros for lane >= 4: harmless
    }

    // direct register -> global partial-row store (positions already aligned)
    float4* sp4 = reinterpret_cast<float4*>(Spart + ((size_t)chunk * ND + n) * HWD);
    sp4[lane]        = acc0;
    sp4[64 + lane]   = acc1;
    sp4[128 + lane]  = acc2;
    if (lane < 4) sp4[192 + lane] = acc3;
}

// ---------------------------------------------------------------------------
// Reduce: S[n,p] = sum over nchunk chunks of Spart[chunk][n][p]. Coalesced;
// Spart is L2-resident (25.6MB across 8 XCDs, just written).
// ---------------------------------------------------------------------------
__global__ void __launch_bounds__(256) reduce_kernel(const float* __restrict__ Spart,
                                                     float* __restrict__ S,
                                                     int nchunk) {
    const int j = blockIdx.x * 256 + threadIdx.x;   // 0 .. 50175
    float s = 0.f;
    for (int ch = 0; ch < nchunk; ++ch)
        s += Spart[(size_t)ch * ND * HWD + j];
    S[j] = s;
}

// ---------------------------------------------------------------------------
// Mult (round-11, measured ~45us): thread -> (n, c0, p4); iterates channels
// c0+64k keeping (n,p4) fixed so its S float4 loads once, reused 16x. Lanes
// cover consecutive p4 -> 1KB/wave linear segments. NT stores keep the out
// stream from evicting x (L3-hot after pass1).
// ---------------------------------------------------------------------------
__global__ void __launch_bounds__(256) mult_kernel(const float* __restrict__ x,
                                                   const float* __restrict__ S,
                                                   float* __restrict__ out) {
    const float4* x4 = reinterpret_cast<const float4*>(x);
    const float4* S4 = reinterpret_cast<const float4*>(S);

    const int tid = blockIdx.x * 256 + threadIdx.x;   // 0 .. 802815
    const int n   = tid / (64 * Q4);                  // 0..63
    const int rem = tid - n * (64 * Q4);
    const int c0  = rem / Q4;                         // 0..63
    const int p4  = rem - c0 * Q4;                    // 0..195

    const float4 sv = S4[n * Q4 + p4];                // one S load, reused 16x
    size_t i4 = ((size_t)(n * CD + c0)) * Q4 + p4;

    #pragma unroll 4
    for (int k = 0; k < 16; ++k, i4 += (size_t)64 * Q4) {
        float4 xv = x4[i4];
        float4 o;
        o.x = xv.x * sv.x;
        o.y = xv.y * sv.y;
        o.z = xv.z * sv.z;
        o.w = xv.w * sv.w;
        __builtin_nontemporal_store(*reinterpret_cast<const f32x4*>(&o),
                                    reinterpret_cast<f32x4*>(out) + i4);
    }
}

extern "C" void kernel_launch(void* const* d_in, const int* in_sizes, int n_in,
                              void* d_out, int out_size, void* d_ws, size_t ws_size,
                              hipStream_t stream) {
    const float* x  = (const float*)d_in[0];   // [N, C, H, W] f32
    const float* w  = (const float*)d_in[1];   // [C] f32
    const float* mu = (const float*)d_in[2];   // scalar (1-elem array)
    float* out = (float*)d_out;

    // prefer 128 chunks (8 ch/wave, 25.8MB scratch); fall back if ws is small
    const size_t row = (size_t)ND * HWD;               // 50176 floats
    int nchunk = (ws_size >= (128 + 1) * row * sizeof(float)) ? 128 : 32;
    const int cpw = CD / nchunk;                       // 8 or 32

    float* Spart = (float*)d_ws;                       // nchunk * 200KB
    float* S     = Spart + (size_t)nchunk * row;       // 200 KB

    // Pass 1: (nchunk/2) x 64 blocks, 128 threads (2 independent waves)
    dim3 g1(nchunk / 2, ND);
    pass1_kernel<<<g1, 128, 0, stream>>>(x, w, mu, Spart, cpw);

    // Reduce: 50176 outputs
    reduce_kernel<<<ND * HWD / 256, 256, 0, stream>>>(Spart, S, nchunk);

    // Mult: 3136 blocks x 256 threads, fixed (n,p4) per thread
    mult_kernel<<<3136, 256, 0, stream>>>(x, S, out);
}

// Round 14
// 98.849 us; speedup vs baseline: 1.3272x; 1.3272x over previous
//
#include <hip/hip_runtime.h>

// Problem shape (fixed by reference): N=64, C=1024, H=W=28 -> HW=784
#define HWD 784
#define Q4  196            // HWD/4 float4 slots per channel row
#define CD  1024
#define ND  64

#define CHPB 32            // channels per pass1 block (4 waves x 8)
#define NCHUNK (CD / CHPB) // 32 partial chunks

typedef float f32x4 __attribute__((ext_vector_type(4)));

__device__ __forceinline__ float4 cam4(float4 v, float wc) {
    float4 r;
    r.x = fmaxf(v.x * wc, 0.f);
    r.y = fmaxf(v.y * wc, 0.f);
    r.z = fmaxf(v.z * wc, 0.f);
    r.w = fmaxf(v.w * wc, 0.f);
    return r;
}
__device__ __forceinline__ float max4(float4 v) {
    return fmaxf(fmaxf(v.x, v.y), fmaxf(v.z, v.w));
}
__device__ __forceinline__ void accdrop(float4& a, float4 c, float thr) {
    a.x += (c.x > thr) ? 0.f : c.x;
    a.y += (c.y > thr) ? 0.f : c.y;
    a.z += (c.z > thr) ? 0.f : c.z;
    a.w += (c.w > thr) ? 0.f : c.w;
}

// ---------------------------------------------------------------------------
// Pass 1 v6: round-12 structure + 2-deep software pipeline on the channel
// loop: channel j+1's 4 float4 loads are issued BEFORE channel j's
// shfl-butterfly (~240 serial cycles), so the memory stream never stalls
// on the cross-lane reduction. +16 VGPR (~70 total) keeps 8 waves/SIMD.
// Block = (chunk of 32 channels, n), 256 threads = 4 waves, LDS combine.
// ---------------------------------------------------------------------------
__global__ void __launch_bounds__(256) pass1_kernel(const float* __restrict__ x,
                                                    const float* __restrict__ w,
                                                    const float* __restrict__ mu_p,
                                                    float* __restrict__ Spart) {
    __shared__ float4 drp[4][197];   // wave stride 197*4 = 788 floats

    const int t = threadIdx.x;
    const int wave = t >> 6;
    const int lane = t & 63;
    const int n = blockIdx.y;
    const int cbase = blockIdx.x * CHPB + wave * 8;
    const float mu = mu_p[0];

    const float4* rows = reinterpret_cast<const float4*>(x + ((size_t)n * CD + cbase) * HWD);

    float4 acc0 = {0.f,0.f,0.f,0.f}, acc1 = {0.f,0.f,0.f,0.f};
    float4 acc2 = {0.f,0.f,0.f,0.f}, acc3 = {0.f,0.f,0.f,0.f};

    // prologue: load channel 0
    float4 v0 = rows[lane];
    float4 v1 = rows[lane + 64];
    float4 v2 = rows[lane + 128];
    float4 v3 = (lane < 4) ? rows[192 + lane] : float4{0.f,0.f,0.f,0.f};

    #pragma unroll 2
    for (int j = 0; j < 8; ++j) {
        // prefetch channel j+1 (independent of this iteration's compute)
        float4 p0 = v0, p1 = v1, p2 = v2, p3 = v3;
        if (j < 7) {
            const float4* rn = rows + (j + 1) * Q4;
            p0 = rn[lane];
            p1 = rn[lane + 64];
            p2 = rn[lane + 128];
            if (lane < 4) p3 = rn[192 + lane];
        }

        const float wc = w[cbase + j];
        float4 c0 = cam4(v0, wc), c1 = cam4(v1, wc);
        float4 c2 = cam4(v2, wc), c3 = cam4(v3, wc);

        float m = fmaxf(fmaxf(max4(c0), max4(c1)), fmaxf(max4(c2), max4(c3)));
        #pragma unroll
        for (int off = 32; off > 0; off >>= 1)
            m = fmaxf(m, __shfl_xor(m, off, 64));
        const float thr = m * mu;

        accdrop(acc0, c0, thr);
        accdrop(acc1, c1, thr);
        accdrop(acc2, c2, thr);
        accdrop(acc3, c3, thr);      // zeros for lane >= 4: harmless

        v0 = p0; v1 = p1; v2 = p2; v3 = p3;
    }

    drp[wave][lane]       = acc0;
    drp[wave][64 + lane]  = acc1;
    drp[wave][128 + lane] = acc2;
    if (lane < 4) drp[wave][192 + lane] = acc3;
    __syncthreads();

    const float* f = reinterpret_cast<const float*>(&drp[0][0]);
    float* sp = Spart + ((size_t)blockIdx.x * ND + n) * HWD;
    for (int p = t; p < HWD; p += 256)
        sp[p] = f[p] + f[788 + p] + f[2 * 788 + p] + f[3 * 788 + p];
}

// ---------------------------------------------------------------------------
// Reduce: S[n,p] = sum over 32 chunks of Spart[chunk][n][p]. Coalesced.
// ---------------------------------------------------------------------------
__global__ void __launch_bounds__(256) reduce_kernel(const float* __restrict__ Spart,
                                                     float* __restrict__ S) {
    const int j = blockIdx.x * 256 + threadIdx.x;   // 0 .. 50175
    float s = 0.f;
    #pragma unroll
    for (int ch = 0; ch < NCHUNK; ++ch)
        s += Spart[(size_t)ch * ND * HWD + j];
    S[j] = s;
}

// ---------------------------------------------------------------------------
// Mult: thread -> (n, c0, p4); iterates channels c0+64k keeping (n,p4) fixed
// so its S float4 loads once, reused 16x. Lanes cover consecutive p4 ->
// 1KB/wave linear segments. unroll 8 for deeper MLP. NT stores keep the out
// stream from evicting x (L3-hot after pass1).
// ---------------------------------------------------------------------------
__global__ void __launch_bounds__(256) mult_kernel(const float* __restrict__ x,
                                                   const float* __restrict__ S,
                                                   float* __restrict__ out) {
    const float4* x4 = reinterpret_cast<const float4*>(x);
    const float4* S4 = reinterpret_cast<const float4*>(S);

    const int tid = blockIdx.x * 256 + threadIdx.x;   // 0 .. 802815
    const int n   = tid / (64 * Q4);                  // 0..63
    const int rem = tid - n * (64 * Q4);
    const int c0  = rem / Q4;                         // 0..63
    const int p4  = rem - c0 * Q4;                    // 0..195

    const float4 sv = S4[n * Q4 + p4];                // one S load, reused 16x
    size_t i4 = ((size_t)(n * CD + c0)) * Q4 + p4;

    #pragma unroll 8
    for (int k = 0; k < 16; ++k, i4 += (size_t)64 * Q4) {
        float4 xv = x4[i4];
        float4 o;
        o.x = xv.x * sv.x;
        o.y = xv.y * sv.y;
        o.z = xv.z * sv.z;
        o.w = xv.w * sv.w;
        __builtin_nontemporal_store(*reinterpret_cast<const f32x4*>(&o),
                                    reinterpret_cast<f32x4*>(out) + i4);
    }
}

extern "C" void kernel_launch(void* const* d_in, const int* in_sizes, int n_in,
                              void* d_out, int out_size, void* d_ws, size_t ws_size,
                              hipStream_t stream) {
    const float* x  = (const float*)d_in[0];   // [N, C, H, W] f32
    const float* w  = (const float*)d_in[1];   // [C] f32
    const float* mu = (const float*)d_in[2];   // scalar (1-elem array)
    float* out = (float*)d_out;

    float* Spart = (float*)d_ws;                       // 32*64*784*4 = 6.4 MB
    float* S     = Spart + (size_t)NCHUNK * ND * HWD;  // 64*784 = 200 KB

    // Pass 1: 32 chunks x 64 samples, 256 threads (4 waves x 8 channels)
    dim3 g1(NCHUNK, ND);
    pass1_kernel<<<g1, 256, 0, stream>>>(x, w, mu, Spart);

    // Reduce: 50176 outputs
    reduce_kernel<<<ND * HWD / 256, 256, 0, stream>>>(Spart, S);

    // Mult: 3136 blocks x 256 threads, fixed (n,p4) per thread, unroll 8
    mult_kernel<<<3136, 256, 0, stream>>>(x, S, out);
}